// Round 4
// baseline (5544.781 us; speedup 1.0000x reference)
//
#include <hip/hip_runtime.h>
#include <stdint.h>

typedef unsigned short u16;
typedef __attribute__((ext_vector_type(8))) __bf16 bf16x8;
typedef __attribute__((ext_vector_type(4))) float f32x4;

#define TTS 256
#define CIN 128
#define FF  256
#define HH  256
#define NSEG 1024

__device__ __forceinline__ u16 f2bf(float f) {
  union { float f; uint32_t u; } v; v.f = f;
  uint32_t r = v.u + 0x7fffu + ((v.u >> 16) & 1u);
  return (u16)(r >> 16);
}
__device__ __forceinline__ float bf2f(u16 h) {
  union { uint32_t u; float f; } v; v.u = ((uint32_t)h) << 16;
  return v.f;
}
__device__ __forceinline__ float sigm(float x) {
  return __builtin_amdgcn_rcpf(1.0f + __expf(-x));
}

// ---------------- K0a: fp32 -> bf16 bulk convert (x) ----------------
__global__ void k_cvt4(const float4* __restrict__ in, ushort4* __restrict__ out, int n4) {
  int i = blockIdx.x * blockDim.x + threadIdx.x;
  int stride = gridDim.x * blockDim.x;
  for (; i < n4; i += stride) {
    float4 v = in[i];
    ushort4 o;
    o.x = f2bf(v.x); o.y = f2bf(v.y); o.z = f2bf(v.z); o.w = f2bf(v.w);
    out[i] = o;
  }
}

// ---------------- K0b: transpose small weight, fp32 -> bf16 ----------------
__global__ void k_transp(const float* __restrict__ in, u16* __restrict__ out, int R, int C) {
  int i = blockIdx.x * blockDim.x + threadIdx.x;
  if (i < R * C) {
    int r = i / C, c = i % C;
    out[(size_t)c * R + r] = f2bf(in[i]);
  }
}

// ---------------- diag: flag init / NaN-Inf scan / flag-encode out ----------------
__global__ void k_flagzero(uint32_t* flag) { *flag = 0u; }

__global__ void k_scan(const ushort4* __restrict__ buf, int n4, int bit,
                       uint32_t* flag) {
  int i = blockIdx.x * blockDim.x + threadIdx.x;
  int stride = gridDim.x * blockDim.x;
  int bad = 0;
  for (; i < n4; i += stride) {
    ushort4 v = buf[i];
    bad |= ((v.x & 0x7FFF) >= 0x7F80) | ((v.y & 0x7FFF) >= 0x7F80) |
           ((v.z & 0x7FFF) >= 0x7F80) | ((v.w & 0x7FFF) >= 0x7F80);
  }
  if (bad) atomicOr(flag, (uint32_t)bit);
}

__global__ void k_flagout(const uint32_t* __restrict__ flag, float* out, int n) {
  uint32_t f = *flag;
  if (f == 0u) return;
  float v = 1000.0f + (float)f;
  int i = blockIdx.x * blockDim.x + threadIdx.x;
  int stride = gridDim.x * blockDim.x;
  for (; i < n; i += stride) out[i] = v;
}

// ---------------- K1: bf16 MFMA GEMM, 128x128 tile, BK=32 ----------------
// Plain-load staging (no global_load_lds). A [M][K], Bt [N][K].
// LDS layout [kchunk 4][row 128][8] -> ds_read_b128 fragments.
// STORE_T: write chunked convT layout [seg][f>>6][f&63][t].
template <bool RELU, bool STORE_T>
__global__ __launch_bounds__(256) void k_gemm(
    const u16* __restrict__ A, const u16* __restrict__ Bt,
    const float* __restrict__ bias, u16* __restrict__ out, int K, int Nld) {
  __shared__ u16 ldsA[4096];
  __shared__ u16 ldsB[4096];
  const int tid  = threadIdx.x;
  const int w    = tid >> 6;
  const int lane = tid & 63;
  const int quad = lane >> 4;
  const int l16  = lane & 15;
  const int m0 = blockIdx.x * 128;
  const int n0 = blockIdx.y * 128;
  const int wm = w >> 1, wn = w & 1;
  const int srow = tid & 127, shalf = tid >> 7;   // staging map

  f32x4 acc[4][4];
#pragma unroll
  for (int i = 0; i < 4; i++)
#pragma unroll
    for (int j = 0; j < 4; j++) acc[i][j] = f32x4{0.f, 0.f, 0.f, 0.f};

  for (int k0 = 0; k0 < K; k0 += 32) {
    bf16x8 va[2], vb[2];
#pragma unroll
    for (int q = 0; q < 2; q++) {
      int c = shalf * 2 + q;
      va[q] = *(const bf16x8*)(A  + (size_t)(m0 + srow) * K + k0 + c * 8);
      vb[q] = *(const bf16x8*)(Bt + (size_t)(n0 + srow) * K + k0 + c * 8);
    }
    __syncthreads();  // prior iteration's ds_reads complete before overwrite
#pragma unroll
    for (int q = 0; q < 2; q++) {
      int c = shalf * 2 + q;
      *(bf16x8*)&ldsA[(c * 128 + srow) * 8] = va[q];
      *(bf16x8*)&ldsB[(c * 128 + srow) * 8] = vb[q];
    }
    __syncthreads();
    bf16x8 a[4], b[4];
#pragma unroll
    for (int i = 0; i < 4; i++)
      a[i] = *(const bf16x8*)&ldsA[(quad * 128 + wm * 64 + i * 16 + l16) * 8];
#pragma unroll
    for (int j = 0; j < 4; j++)
      b[j] = *(const bf16x8*)&ldsB[(quad * 128 + wn * 64 + j * 16 + l16) * 8];
#pragma unroll
    for (int i = 0; i < 4; i++)
#pragma unroll
      for (int j = 0; j < 4; j++)
        acc[i][j] = __builtin_amdgcn_mfma_f32_16x16x32_bf16(a[i], b[j], acc[i][j], 0, 0, 0);
  }

#pragma unroll
  for (int j = 0; j < 4; j++) {
    int col = n0 + wn * 64 + j * 16 + l16;
    float bv = bias[col];
#pragma unroll
    for (int i = 0; i < 4; i++) {
      int row0 = m0 + wm * 64 + i * 16 + quad * 4;  // 4 consecutive rows
      if (STORE_T) {
        int nseg = row0 >> 8, tt0 = row0 & 255;
        ushort4 o;
        float v0 = acc[i][j][0] + bv, v1 = acc[i][j][1] + bv;
        float v2 = acc[i][j][2] + bv, v3 = acc[i][j][3] + bv;
        if (RELU) {
          v0 = fmaxf(v0, 0.f); v1 = fmaxf(v1, 0.f);
          v2 = fmaxf(v2, 0.f); v3 = fmaxf(v3, 0.f);
        }
        o.x = f2bf(v0); o.y = f2bf(v1); o.z = f2bf(v2); o.w = f2bf(v3);
        *(ushort4*)&out[(size_t)nseg * 65536 + (size_t)(col >> 6) * 16384 +
                        (col & 63) * 256 + tt0] = o;
      } else {
#pragma unroll
        for (int r = 0; r < 4; r++) {
          float v = acc[i][j][r] + bv;
          if (RELU) v = fmaxf(v, 0.f);
          out[(size_t)(row0 + r) * Nld + col] = f2bf(v);
        }
      }
    }
  }
}

// ---------------- K2: attention (in-place on xac), plain-load staging ----------------
// Block (seg, c4) owns 32KB region: reads conv [f&63][t], writes x_att [t][f&63].
__global__ __launch_bounds__(256) void k_attn(
    u16* xac,
    const u16* __restrict__ Wt,       // attn_w^T: [t'][t] 256x256
    const float* __restrict__ attn_b) {
  __shared__ u16 ldsW[8192];          // per-stage Wt tile [c 4][t' 256][8]
  __shared__ u16 ldsC[16384];         // conv resident [tchunk 32][f 64][8]
  __shared__ float redmax[4][64];
  __shared__ float redsum[4][64];
  const int tid  = threadIdx.x;
  const int w    = tid >> 6;
  const int lane = tid & 63;
  const int quad = lane >> 4;
  const int l16  = lane & 15;
  const int seg = blockIdx.x;
  const int c4  = blockIdx.y;
  u16* reg = xac + (size_t)seg * 65536 + (size_t)c4 * 16384;

  // stage conv fully: thread (f = tid&63, g = tid>>6) copies 8 chunks
  {
    const int f = tid & 63, g = tid >> 6;
#pragma unroll
    for (int u = 0; u < 8; u++) {
      int tch = g * 8 + u;   // 8 consecutive t values tch*8..tch*8+7
      *(bf16x8*)&ldsC[(tch * 64 + f) * 8] =
          *(const bf16x8*)(reg + (size_t)f * 256 + tch * 8);
    }
  }

  f32x4 acc[4][4];
#pragma unroll
  for (int i = 0; i < 4; i++)
#pragma unroll
    for (int j = 0; j < 4; j++) acc[i][j] = f32x4{0.f, 0.f, 0.f, 0.f};

  for (int s = 0; s < 8; s++) {
    int k0 = s * 32;
    bf16x8 vw[4];
#pragma unroll
    for (int c = 0; c < 4; c++)
      vw[c] = *(const bf16x8*)(Wt + (size_t)tid * 256 + k0 + c * 8);
    __syncthreads();  // also covers initial ldsC stores at s=0
#pragma unroll
    for (int c = 0; c < 4; c++)
      *(bf16x8*)&ldsW[(c * 256 + tid) * 8] = vw[c];
    __syncthreads();
    bf16x8 a[4], b[4];
#pragma unroll
    for (int i = 0; i < 4; i++)
      a[i] = *(const bf16x8*)&ldsW[(quad * 256 + w * 64 + i * 16 + l16) * 8];
#pragma unroll
    for (int j = 0; j < 4; j++)
      b[j] = *(const bf16x8*)&ldsC[((s * 4 + quad) * 64 + j * 16 + l16) * 8];
#pragma unroll
    for (int i = 0; i < 4; i++)
#pragma unroll
      for (int j = 0; j < 4; j++)
        acc[i][j] = __builtin_amdgcn_mfma_f32_16x16x32_bf16(a[i], b[j], acc[i][j], 0, 0, 0);
  }

  // + attn_b[t']
#pragma unroll
  for (int i = 0; i < 4; i++)
#pragma unroll
    for (int r = 0; r < 4; r++) {
      float ab = attn_b[w * 64 + i * 16 + quad * 4 + r];
#pragma unroll
      for (int j = 0; j < 4; j++) acc[i][j][r] += ab;
    }

  // softmax over t' (rows) per f column
  float lmax[4];
#pragma unroll
  for (int j = 0; j < 4; j++) {
    float m = -1e30f;
#pragma unroll
    for (int i = 0; i < 4; i++)
#pragma unroll
      for (int r = 0; r < 4; r++) m = fmaxf(m, acc[i][j][r]);
    m = fmaxf(m, __shfl_xor(m, 16));
    m = fmaxf(m, __shfl_xor(m, 32));
    lmax[j] = m;
  }
  __syncthreads();  // ldsW/ldsC reads done; red buffers reused freely
  if (quad == 0) {
#pragma unroll
    for (int j = 0; j < 4; j++) redmax[w][j * 16 + l16] = lmax[j];
  }
  __syncthreads();
  float gmax[4];
#pragma unroll
  for (int j = 0; j < 4; j++) {
    int c = j * 16 + l16;
    gmax[j] = fmaxf(fmaxf(redmax[0][c], redmax[1][c]), fmaxf(redmax[2][c], redmax[3][c]));
  }
  float lsum[4];
#pragma unroll
  for (int j = 0; j < 4; j++) {
    float sacc = 0.f;
#pragma unroll
    for (int i = 0; i < 4; i++)
#pragma unroll
      for (int r = 0; r < 4; r++) {
        float e = __expf(acc[i][j][r] - gmax[j]);
        acc[i][j][r] = e;
        sacc += e;
      }
    sacc += __shfl_xor(sacc, 16);
    sacc += __shfl_xor(sacc, 32);
    lsum[j] = sacc;
  }
  if (quad == 0) {
#pragma unroll
    for (int j = 0; j < 4; j++) redsum[w][j * 16 + l16] = lsum[j];
  }
  __syncthreads();
  float rinv[4];
#pragma unroll
  for (int j = 0; j < 4; j++) {
    int c = j * 16 + l16;
    rinv[j] = 1.0f / (redsum[0][c] + redsum[1][c] + redsum[2][c] + redsum[3][c]);
  }

  // x_att[t][f] = conv[t][f] * probs[f][t]; overwrite own region
#pragma unroll
  for (int i = 0; i < 4; i++) {
#pragma unroll
    for (int r = 0; r < 4; r++) {
      int tp = w * 64 + i * 16 + quad * 4 + r;
#pragma unroll
      for (int j = 0; j < 4; j++) {
        int fl = j * 16 + l16;
        float cv = bf2f(ldsC[((tp >> 3) * 64 + fl) * 8 + (tp & 7)]);
        float xa = acc[i][j][r] * rinv[j] * cv;
        reg[(size_t)tp * 64 + fl] = f2bf(xa);
      }
    }
  }
}

// ---------------- K4: fused gates-GEMM + GRU scan (simplified) ----------------
// 32 blocks x 512 thr, 32 segs/block. Single hb buffer, 2 barriers/step,
// x fragments loaded directly from global (contiguous 16B per lane).
__global__ __launch_bounds__(512) void k_gruf(
    const u16* __restrict__ xac,   // x_att chunked [seg][4][t 256][f 64]
    const u16* __restrict__ Ut,    // gru_u^T [768][256]
    const u16* __restrict__ Wg,    // gru_w^T [768][256]
    const float* __restrict__ gb,  // gru_b [2][768]
    float* __restrict__ out) {     // [NSEG][256]
  __shared__ u16 hb[32 * 264];     // bf16 h, row stride 264
  const int tid  = threadIdx.x;
  const int wc   = tid >> 6;       // 0..7: owns cols wc*32..wc*32+31 (z,r,h)
  const int lane = tid & 63;
  const int quad = lane >> 4;
  const int l16  = lane & 15;
  const int n0 = blockIdx.x * 32;

  for (int i = tid; i < 32 * 264; i += 512) hb[i] = 0;

  float bsZ[2], bsR[2], biH[2], brH[2];
#pragma unroll
  for (int jj = 0; jj < 2; jj++) {
    int col = wc * 32 + jj * 16 + l16;
    bsZ[jj] = gb[col] + gb[768 + col];
    bsR[jj] = gb[256 + col] + gb[768 + 256 + col];
    biH[jj] = gb[512 + col];
    brH[jj] = gb[768 + 512 + col];
  }

  // B-operand bases: ti 0,1=z 2,3=r 4,5=h
  const u16* pU[6]; const u16* pW[6];
#pragma unroll
  for (int ti = 0; ti < 6; ti++) {
    int colt = (ti >> 1) * 256 + wc * 32 + (ti & 1) * 16;
    size_t off = (size_t)(colt + l16) * 256 + quad * 8;
    pU[ti] = Ut + off; pW[ti] = Wg + off;
  }

  // direct x A-fragment bases: lane l16 -> seg row within mt-tile
  const u16* xbase[2];
#pragma unroll
  for (int mt = 0; mt < 2; mt++)
    xbase[mt] = xac + (size_t)(n0 + mt * 16 + l16) * 65536;

  float hreg[2][2][4];
#pragma unroll
  for (int mt = 0; mt < 2; mt++)
#pragma unroll
    for (int jj = 0; jj < 2; jj++)
#pragma unroll
      for (int r = 0; r < 4; r++) hreg[mt][jj][r] = 0.f;

  __syncthreads();

  for (int t = 0; t < TTS; t++) {
    f32x4 azr[2][4], arh[2][2], agh[2][2];
#pragma unroll
    for (int mt = 0; mt < 2; mt++) {
#pragma unroll
      for (int ti = 0; ti < 4; ti++) azr[mt][ti] = f32x4{0.f, 0.f, 0.f, 0.f};
#pragma unroll
      for (int jj = 0; jj < 2; jj++) {
        arh[mt][jj] = f32x4{0.f, 0.f, 0.f, 0.f};
        agh[mt][jj] = f32x4{0.f, 0.f, 0.f, 0.f};
      }
    }
#pragma unroll
    for (int s = 0; s < 8; s++) {
      bf16x8 bu[6], bw[6];
#pragma unroll
      for (int ti = 0; ti < 6; ti++) {
        bu[ti] = *(const bf16x8*)(pU[ti] + s * 32);
        bw[ti] = *(const bf16x8*)(pW[ti] + s * 32);
      }
      // f = s*32 + quad*8 (+jj): chunk = s>>1, in-chunk = (s&1)*32 + quad*8
      size_t xoff = (size_t)(s >> 1) * 16384 + (size_t)t * 64 + (s & 1) * 32 + quad * 8;
#pragma unroll
      for (int mt = 0; mt < 2; mt++) {
        bf16x8 ah = *(const bf16x8*)&hb[(mt * 16 + l16) * 264 + s * 32 + quad * 8];
        bf16x8 ax = *(const bf16x8*)(xbase[mt] + xoff);
#pragma unroll
        for (int ti = 0; ti < 4; ti++) {
          azr[mt][ti] = __builtin_amdgcn_mfma_f32_16x16x32_bf16(ah, bu[ti], azr[mt][ti], 0, 0, 0);
          azr[mt][ti] = __builtin_amdgcn_mfma_f32_16x16x32_bf16(ax, bw[ti], azr[mt][ti], 0, 0, 0);
        }
#pragma unroll
        for (int jj = 0; jj < 2; jj++) {
          arh[mt][jj] = __builtin_amdgcn_mfma_f32_16x16x32_bf16(ah, bu[4 + jj], arh[mt][jj], 0, 0, 0);
          agh[mt][jj] = __builtin_amdgcn_mfma_f32_16x16x32_bf16(ax, bw[4 + jj], agh[mt][jj], 0, 0, 0);
        }
      }
    }
    __syncthreads();   // all hb reads complete before overwrite

#pragma unroll
    for (int mt = 0; mt < 2; mt++)
#pragma unroll
      for (int jj = 0; jj < 2; jj++)
#pragma unroll
        for (int r = 0; r < 4; r++) {
          int seg = mt * 16 + quad * 4 + r;
          int col = wc * 32 + jj * 16 + l16;
          float z  = sigm(azr[mt][jj][r] + bsZ[jj]);
          float rg = sigm(azr[mt][2 + jj][r] + bsR[jj]);
          float hh = fmaxf(agh[mt][jj][r] + biH[jj] + rg * (arh[mt][jj][r] + brH[jj]), 0.f);
          float hn = z * hreg[mt][jj][r] + (1.0f - z) * hh;
          hreg[mt][jj][r] = hn;
          hb[seg * 264 + col] = f2bf(hn);
        }
    __syncthreads();   // writes visible before next step's reads
  }

#pragma unroll
  for (int mt = 0; mt < 2; mt++)
#pragma unroll
    for (int jj = 0; jj < 2; jj++)
#pragma unroll
      for (int r = 0; r < 4; r++) {
        int seg = mt * 16 + quad * 4 + r;
        int col = wc * 32 + jj * 16 + l16;
        out[(size_t)(n0 + seg) * 256 + col] = hreg[mt][jj][r];
      }
}

// ---------------- host ----------------
extern "C" void kernel_launch(void* const* d_in, const int* in_sizes, int n_in,
                              void* d_out, int out_size, void* d_ws, size_t ws_size,
                              hipStream_t stream) {
  (void)in_sizes; (void)n_in; (void)out_size;
  const float* x      = (const float*)d_in[0];
  const float* conv_w = (const float*)d_in[1];
  const float* conv_b = (const float*)d_in[2];
  const float* attn_w = (const float*)d_in[3];
  const float* attn_b = (const float*)d_in[4];
  const float* gru_w  = (const float*)d_in[5];
  const float* gru_u  = (const float*)d_in[6];
  const float* gru_b  = (const float*)d_in[7];

  const size_t NEEDED = 202309696;
  if (ws_size < NEEDED) return;  // clean failure (absmax ~= max|ref|, all-zero out)
  char* ws = (char*)d_ws;
  u16* xac     = (u16*)(ws);                  // 134217728 B: convT then x_att (chunked, aliased)
  u16* x_bf    = (u16*)(ws + 134217728);      //  67108864 B
  u16* conv_wT = (u16*)(ws + 201326592);      //     65536 B [f][c]
  u16* attn_wT = (u16*)(ws + 201392128);      //    131072 B [t'][t]
  u16* gru_wT  = (u16*)(ws + 201523200);      //    393216 B [j][f]
  u16* gru_uT  = (u16*)(ws + 201916416);      //    393216 B [j][k]
  uint32_t* flag = (uint32_t*)(ws + 202309632);

  hipLaunchKernelGGL(k_cvt4, dim3(4096), dim3(256), 0, stream,
                     (const float4*)x, (ushort4*)x_bf, 8388608);
  hipLaunchKernelGGL(k_transp, dim3(128), dim3(256), 0, stream, conv_w, conv_wT, 128, 256);
  hipLaunchKernelGGL(k_transp, dim3(256), dim3(256), 0, stream, attn_w, attn_wT, 256, 256);
  hipLaunchKernelGGL(k_transp, dim3(768), dim3(256), 0, stream, gru_w, gru_wT, 256, 768);
  hipLaunchKernelGGL(k_transp, dim3(768), dim3(256), 0, stream, gru_u, gru_uT, 256, 768);
  hipLaunchKernelGGL(k_flagzero, dim3(1), dim3(1), 0, stream, flag);

  // K1: conv = relu(x @ conv_w + b) -> chunked convT layout in xac
  hipLaunchKernelGGL((k_gemm<true, true>), dim3(2048, 2), dim3(256), 0, stream,
                     x_bf, conv_wT, conv_b, xac, 128, 0);
  hipLaunchKernelGGL(k_scan, dim3(1024), dim3(256), 0, stream,
                     (const ushort4*)xac, 16777216, 1, flag);
  // K2: attention softmax + multiply, in place on xac
  hipLaunchKernelGGL(k_attn, dim3(1024, 4), dim3(256), 0, stream,
                     xac, attn_wT, attn_b);
  hipLaunchKernelGGL(k_scan, dim3(1024), dim3(256), 0, stream,
                     (const ushort4*)xac, 16777216, 2, flag);
  // K4: fused gates GEMM + GRU scan -> d_out (fp32)
  hipLaunchKernelGGL(k_gruf, dim3(32), dim3(512), 0, stream,
                     xac, gru_uT, gru_wT, gru_b, (float*)d_out);
  // diag: if upstream NaN/Inf detected, overwrite out with 1000+flag
  hipLaunchKernelGGL(k_flagout, dim3(256), dim3(256), 0, stream,
                     flag, (float*)d_out, 262144);
}

// Round 5
// 5504.188 us; speedup vs baseline: 1.0074x; 1.0074x over previous
//
#include <hip/hip_runtime.h>
#include <stdint.h>

typedef unsigned short u16;
typedef __attribute__((ext_vector_type(8))) __bf16 bf16x8;
typedef __attribute__((ext_vector_type(4))) float f32x4;

#define TTS 256
#define CIN 128
#define FF  256
#define HH  256
#define NSEG 1024

__device__ __forceinline__ u16 f2bf(float f) {
  union { float f; uint32_t u; } v; v.f = f;
  uint32_t r = v.u + 0x7fffu + ((v.u >> 16) & 1u);
  return (u16)(r >> 16);
}
__device__ __forceinline__ float bf2f(u16 h) {
  union { uint32_t u; float f; } v; v.u = ((uint32_t)h) << 16;
  return v.f;
}
__device__ __forceinline__ float sigm(float x) {
  return __builtin_amdgcn_rcpf(1.0f + __expf(-x));
}

// ---------------- K0a: fp32 -> bf16 bulk convert (x) ----------------
__global__ void k_cvt4(const float4* __restrict__ in, ushort4* __restrict__ out, int n4) {
  int i = blockIdx.x * blockDim.x + threadIdx.x;
  int stride = gridDim.x * blockDim.x;
  for (; i < n4; i += stride) {
    float4 v = in[i];
    ushort4 o;
    o.x = f2bf(v.x); o.y = f2bf(v.y); o.z = f2bf(v.z); o.w = f2bf(v.w);
    out[i] = o;
  }
}

// ---------------- K0b: transpose small weight, fp32 -> bf16 ----------------
__global__ void k_transp(const float* __restrict__ in, u16* __restrict__ out, int R, int C) {
  int i = blockIdx.x * blockDim.x + threadIdx.x;
  if (i < R * C) {
    int r = i / C, c = i % C;
    out[(size_t)c * R + r] = f2bf(in[i]);
  }
}

// ---------------- K1/K3: bf16 MFMA GEMM, 128x128 tile, BK=32 ----------------
// A row-major [M][K] (or chunked x_att layout if ACHUNK). Bt [N][K].
// STORE_T: write chunked convT layout [seg][f>>6][f&63][t].
template <bool RELU, bool STORE_T, bool ACHUNK>
__global__ __launch_bounds__(256) void k_gemm(
    const u16* __restrict__ A, const u16* __restrict__ Bt,
    const float* __restrict__ bias, u16* __restrict__ out, int K, int Nld) {
  __shared__ u16 ldsA[4096];
  __shared__ u16 ldsB[4096];
  const int tid  = threadIdx.x;
  const int w    = tid >> 6;
  const int lane = tid & 63;
  const int quad = lane >> 4;
  const int l16  = lane & 15;
  const int m0 = blockIdx.x * 128;
  const int n0 = blockIdx.y * 128;
  const int wm = w >> 1, wn = w & 1;
  const int srow = tid & 127, shalf = tid >> 7;   // staging map

  f32x4 acc[4][4];
#pragma unroll
  for (int i = 0; i < 4; i++)
#pragma unroll
    for (int j = 0; j < 4; j++) acc[i][j] = f32x4{0.f, 0.f, 0.f, 0.f};

  for (int k0 = 0; k0 < K; k0 += 32) {
    bf16x8 va[2], vb[2];
#pragma unroll
    for (int q = 0; q < 2; q++) {
      int c = shalf * 2 + q;
      if (ACHUNK) {
        // x_att chunked: [seg][k>>6][t][64]; all 128 rows in one seg
        int seg = m0 >> 8, t0 = m0 & 255;
        int kk = k0 + c * 8;
        va[q] = *(const bf16x8*)(A + (size_t)seg * 65536 +
                                 (size_t)(kk >> 6) * 16384 + (t0 + srow) * 64 + (kk & 63));
      } else {
        va[q] = *(const bf16x8*)(A + (size_t)(m0 + srow) * K + k0 + c * 8);
      }
      vb[q] = *(const bf16x8*)(Bt + (size_t)(n0 + srow) * K + k0 + c * 8);
    }
    __syncthreads();  // prior iteration's ds_reads complete before overwrite
#pragma unroll
    for (int q = 0; q < 2; q++) {
      int c = shalf * 2 + q;
      *(bf16x8*)&ldsA[(c * 128 + srow) * 8] = va[q];
      *(bf16x8*)&ldsB[(c * 128 + srow) * 8] = vb[q];
    }
    __syncthreads();
    bf16x8 a[4], b[4];
#pragma unroll
    for (int i = 0; i < 4; i++)
      a[i] = *(const bf16x8*)&ldsA[(quad * 128 + wm * 64 + i * 16 + l16) * 8];
#pragma unroll
    for (int j = 0; j < 4; j++)
      b[j] = *(const bf16x8*)&ldsB[(quad * 128 + wn * 64 + j * 16 + l16) * 8];
#pragma unroll
    for (int i = 0; i < 4; i++)
#pragma unroll
      for (int j = 0; j < 4; j++)
        acc[i][j] = __builtin_amdgcn_mfma_f32_16x16x32_bf16(a[i], b[j], acc[i][j], 0, 0, 0);
  }

#pragma unroll
  for (int j = 0; j < 4; j++) {
    int col = n0 + wn * 64 + j * 16 + l16;
    float bv = bias[col];
#pragma unroll
    for (int i = 0; i < 4; i++) {
      int row0 = m0 + wm * 64 + i * 16 + quad * 4;  // 4 consecutive rows
      if (STORE_T) {
        int nseg = row0 >> 8, tt0 = row0 & 255;
        ushort4 o;
        float v0 = acc[i][j][0] + bv, v1 = acc[i][j][1] + bv;
        float v2 = acc[i][j][2] + bv, v3 = acc[i][j][3] + bv;
        if (RELU) {
          v0 = fmaxf(v0, 0.f); v1 = fmaxf(v1, 0.f);
          v2 = fmaxf(v2, 0.f); v3 = fmaxf(v3, 0.f);
        }
        o.x = f2bf(v0); o.y = f2bf(v1); o.z = f2bf(v2); o.w = f2bf(v3);
        *(ushort4*)&out[(size_t)nseg * 65536 + (size_t)(col >> 6) * 16384 +
                        (col & 63) * 256 + tt0] = o;
      } else {
#pragma unroll
        for (int r = 0; r < 4; r++) {
          float v = acc[i][j][r] + bv;
          if (RELU) v = fmaxf(v, 0.f);
          out[(size_t)(row0 + r) * Nld + col] = f2bf(v);
        }
      }
    }
  }
}

// ---------------- K2: attention (in-place on xac), plain-load staging ----------------
__global__ __launch_bounds__(256) void k_attn(
    u16* xac,
    const u16* __restrict__ Wt,       // attn_w^T: [t'][t] 256x256
    const float* __restrict__ attn_b) {
  __shared__ u16 ldsW[8192];          // per-stage Wt tile [c 4][t' 256][8]
  __shared__ u16 ldsC[16384];         // conv resident [tchunk 32][f 64][8]
  __shared__ float redmax[4][64];
  __shared__ float redsum[4][64];
  const int tid  = threadIdx.x;
  const int w    = tid >> 6;
  const int lane = tid & 63;
  const int quad = lane >> 4;
  const int l16  = lane & 15;
  const int seg = blockIdx.x;
  const int c4  = blockIdx.y;
  u16* reg = xac + (size_t)seg * 65536 + (size_t)c4 * 16384;

  {
    const int f = tid & 63, g = tid >> 6;
#pragma unroll
    for (int u = 0; u < 8; u++) {
      int tch = g * 8 + u;
      *(bf16x8*)&ldsC[(tch * 64 + f) * 8] =
          *(const bf16x8*)(reg + (size_t)f * 256 + tch * 8);
    }
  }

  f32x4 acc[4][4];
#pragma unroll
  for (int i = 0; i < 4; i++)
#pragma unroll
    for (int j = 0; j < 4; j++) acc[i][j] = f32x4{0.f, 0.f, 0.f, 0.f};

  for (int s = 0; s < 8; s++) {
    int k0 = s * 32;
    bf16x8 vw[4];
#pragma unroll
    for (int c = 0; c < 4; c++)
      vw[c] = *(const bf16x8*)(Wt + (size_t)tid * 256 + k0 + c * 8);
    __syncthreads();
#pragma unroll
    for (int c = 0; c < 4; c++)
      *(bf16x8*)&ldsW[(c * 256 + tid) * 8] = vw[c];
    __syncthreads();
    bf16x8 a[4], b[4];
#pragma unroll
    for (int i = 0; i < 4; i++)
      a[i] = *(const bf16x8*)&ldsW[(quad * 256 + w * 64 + i * 16 + l16) * 8];
#pragma unroll
    for (int j = 0; j < 4; j++)
      b[j] = *(const bf16x8*)&ldsC[((s * 4 + quad) * 64 + j * 16 + l16) * 8];
#pragma unroll
    for (int i = 0; i < 4; i++)
#pragma unroll
      for (int j = 0; j < 4; j++)
        acc[i][j] = __builtin_amdgcn_mfma_f32_16x16x32_bf16(a[i], b[j], acc[i][j], 0, 0, 0);
  }

#pragma unroll
  for (int i = 0; i < 4; i++)
#pragma unroll
    for (int r = 0; r < 4; r++) {
      float ab = attn_b[w * 64 + i * 16 + quad * 4 + r];
#pragma unroll
      for (int j = 0; j < 4; j++) acc[i][j][r] += ab;
    }

  float lmax[4];
#pragma unroll
  for (int j = 0; j < 4; j++) {
    float m = -1e30f;
#pragma unroll
    for (int i = 0; i < 4; i++)
#pragma unroll
      for (int r = 0; r < 4; r++) m = fmaxf(m, acc[i][j][r]);
    m = fmaxf(m, __shfl_xor(m, 16));
    m = fmaxf(m, __shfl_xor(m, 32));
    lmax[j] = m;
  }
  __syncthreads();
  if (quad == 0) {
#pragma unroll
    for (int j = 0; j < 4; j++) redmax[w][j * 16 + l16] = lmax[j];
  }
  __syncthreads();
  float gmax[4];
#pragma unroll
  for (int j = 0; j < 4; j++) {
    int c = j * 16 + l16;
    gmax[j] = fmaxf(fmaxf(redmax[0][c], redmax[1][c]), fmaxf(redmax[2][c], redmax[3][c]));
  }
  float lsum[4];
#pragma unroll
  for (int j = 0; j < 4; j++) {
    float sacc = 0.f;
#pragma unroll
    for (int i = 0; i < 4; i++)
#pragma unroll
      for (int r = 0; r < 4; r++) {
        float e = __expf(acc[i][j][r] - gmax[j]);
        acc[i][j][r] = e;
        sacc += e;
      }
    sacc += __shfl_xor(sacc, 16);
    sacc += __shfl_xor(sacc, 32);
    lsum[j] = sacc;
  }
  if (quad == 0) {
#pragma unroll
    for (int j = 0; j < 4; j++) redsum[w][j * 16 + l16] = lsum[j];
  }
  __syncthreads();
  float rinv[4];
#pragma unroll
  for (int j = 0; j < 4; j++) {
    int c = j * 16 + l16;
    rinv[j] = 1.0f / (redsum[0][c] + redsum[1][c] + redsum[2][c] + redsum[3][c]);
  }

#pragma unroll
  for (int i = 0; i < 4; i++) {
#pragma unroll
    for (int r = 0; r < 4; r++) {
      int tp = w * 64 + i * 16 + quad * 4 + r;
#pragma unroll
      for (int j = 0; j < 4; j++) {
        int fl = j * 16 + l16;
        float cv = bf2f(ldsC[((tp >> 3) * 64 + fl) * 8 + (tp & 7)]);
        float xa = acc[i][j][r] * rinv[j] * cv;
        reg[(size_t)tp * 64 + fl] = f2bf(xa);
      }
    }
  }
}

// ---------------- K4-fast: GRU scan with precomputed gates ----------------
// 64 blocks x 1024 thr, 16 segs/block. gates[m=seg*256+t][768] already has
// +bi. Ut: 4 K-chunks register-resident, 4 streamed from L2 per step
// (h-independent addresses -> prefetchable). h in LDS, 2 barriers/step.
__global__ __launch_bounds__(1024) void k_gruf2(
    const u16* __restrict__ gates,  // [NSEG*TTS][768] bf16 (x@W + bi)
    const u16* __restrict__ Ut,     // gru_u^T [768][256]
    const float* __restrict__ br,   // gru_b[1]: [768]
    float* __restrict__ out) {      // [NSEG][256]
  __shared__ u16 hb[16 * 264];      // bf16 h, row stride 264 (2-way banks only)
  const int tid  = threadIdx.x;
  const int w    = tid >> 6;        // 0..15: col w*16+l16 of each gate
  const int lane = tid & 63;
  const int quad = lane >> 4;
  const int l16  = lane & 15;
  const int n0 = blockIdx.x * 16;
  const int col = w * 16 + l16;

  for (int i = tid; i < 16 * 264; i += 1024) hb[i] = 0;

  const float brZ = br[col];
  const float brR = br[256 + col];
  const float brH = br[512 + col];

  // B-fragment pointers per gate
  const u16* pU[3];
#pragma unroll
  for (int g = 0; g < 3; g++)
    pU[g] = Ut + (size_t)(g * 256 + col) * 256 + quad * 8;

  // resident Ut chunks 0..3 (48 VGPR)
  bf16x8 ur[3][4];
#pragma unroll
  for (int g = 0; g < 3; g++)
#pragma unroll
    for (int s = 0; s < 4; s++) ur[g][s] = *(const bf16x8*)(pU[g] + s * 32);

  // gates row bases for this lane's 4 segs
  const u16* gb0 = gates + (size_t)(n0 + quad * 4) * 256 * 768 + col;
  const size_t segstr = (size_t)256 * 768;

  float hreg[4] = {0.f, 0.f, 0.f, 0.f};
  __syncthreads();

  for (int t = 0; t < TTS; t++) {
    // prefetch gates[t] (no h dependency)
    float gz[4], gr[4], gh[4];
#pragma unroll
    for (int r = 0; r < 4; r++) {
      const u16* g = gb0 + segstr * r + (size_t)t * 768;
      gz[r] = bf2f(g[0]); gr[r] = bf2f(g[256]); gh[r] = bf2f(g[512]);
    }
    // stream Ut chunks 4-5 (L2 hit, h-independent)
    bf16x8 us0[3][2];
#pragma unroll
    for (int g = 0; g < 3; g++)
#pragma unroll
      for (int s = 0; s < 2; s++) us0[g][s] = *(const bf16x8*)(pU[g] + (4 + s) * 32);

    f32x4 acc[3];
#pragma unroll
    for (int g = 0; g < 3; g++) acc[g] = f32x4{0.f, 0.f, 0.f, 0.f};

#pragma unroll
    for (int s = 0; s < 4; s++) {
      bf16x8 a = *(const bf16x8*)&hb[l16 * 264 + s * 32 + quad * 8];
#pragma unroll
      for (int g = 0; g < 3; g++)
        acc[g] = __builtin_amdgcn_mfma_f32_16x16x32_bf16(a, ur[g][s], acc[g], 0, 0, 0);
    }
    bf16x8 us1[3][2];
#pragma unroll
    for (int g = 0; g < 3; g++)
#pragma unroll
      for (int s = 0; s < 2; s++) us1[g][s] = *(const bf16x8*)(pU[g] + (6 + s) * 32);
#pragma unroll
    for (int s = 0; s < 2; s++) {
      bf16x8 a = *(const bf16x8*)&hb[l16 * 264 + (4 + s) * 32 + quad * 8];
#pragma unroll
      for (int g = 0; g < 3; g++)
        acc[g] = __builtin_amdgcn_mfma_f32_16x16x32_bf16(a, us0[g][s], acc[g], 0, 0, 0);
    }
#pragma unroll
    for (int s = 0; s < 2; s++) {
      bf16x8 a = *(const bf16x8*)&hb[l16 * 264 + (6 + s) * 32 + quad * 8];
#pragma unroll
      for (int g = 0; g < 3; g++)
        acc[g] = __builtin_amdgcn_mfma_f32_16x16x32_bf16(a, us1[g][s], acc[g], 0, 0, 0);
    }
    __syncthreads();   // all hb reads complete before overwrite

#pragma unroll
    for (int r = 0; r < 4; r++) {
      float z  = sigm(acc[0][r] + gz[r] + brZ);
      float rg = sigm(acc[1][r] + gr[r] + brR);
      float hh = fmaxf(gh[r] + rg * (acc[2][r] + brH), 0.f);
      float hn = z * hreg[r] + (1.0f - z) * hh;
      hreg[r] = hn;
      hb[(quad * 4 + r) * 264 + col] = f2bf(hn);
    }
    __syncthreads();   // writes visible before next step's reads
  }

#pragma unroll
  for (int r = 0; r < 4; r++)
    out[(size_t)(n0 + quad * 4 + r) * 256 + col] = hreg[r];
}

// ---------------- K4-fallback: round-4 fused scan (known-correct) ----------------
__global__ __launch_bounds__(512) void k_gruf(
    const u16* __restrict__ xac, const u16* __restrict__ Ut,
    const u16* __restrict__ Wg, const float* __restrict__ gb,
    float* __restrict__ out) {
  __shared__ u16 hb[32 * 264];
  const int tid  = threadIdx.x;
  const int wc   = tid >> 6;
  const int lane = tid & 63;
  const int quad = lane >> 4;
  const int l16  = lane & 15;
  const int n0 = blockIdx.x * 32;

  for (int i = tid; i < 32 * 264; i += 512) hb[i] = 0;

  float bsZ[2], bsR[2], biH[2], brH[2];
#pragma unroll
  for (int jj = 0; jj < 2; jj++) {
    int col = wc * 32 + jj * 16 + l16;
    bsZ[jj] = gb[col] + gb[768 + col];
    bsR[jj] = gb[256 + col] + gb[768 + 256 + col];
    biH[jj] = gb[512 + col];
    brH[jj] = gb[768 + 512 + col];
  }
  const u16* pU[6]; const u16* pW[6];
#pragma unroll
  for (int ti = 0; ti < 6; ti++) {
    int colt = (ti >> 1) * 256 + wc * 32 + (ti & 1) * 16;
    size_t off = (size_t)(colt + l16) * 256 + quad * 8;
    pU[ti] = Ut + off; pW[ti] = Wg + off;
  }
  const u16* xbase[2];
#pragma unroll
  for (int mt = 0; mt < 2; mt++)
    xbase[mt] = xac + (size_t)(n0 + mt * 16 + l16) * 65536;

  float hreg[2][2][4];
#pragma unroll
  for (int mt = 0; mt < 2; mt++)
#pragma unroll
    for (int jj = 0; jj < 2; jj++)
#pragma unroll
      for (int r = 0; r < 4; r++) hreg[mt][jj][r] = 0.f;
  __syncthreads();

  for (int t = 0; t < TTS; t++) {
    f32x4 azr[2][4], arh[2][2], agh[2][2];
#pragma unroll
    for (int mt = 0; mt < 2; mt++) {
#pragma unroll
      for (int ti = 0; ti < 4; ti++) azr[mt][ti] = f32x4{0.f, 0.f, 0.f, 0.f};
#pragma unroll
      for (int jj = 0; jj < 2; jj++) {
        arh[mt][jj] = f32x4{0.f, 0.f, 0.f, 0.f};
        agh[mt][jj] = f32x4{0.f, 0.f, 0.f, 0.f};
      }
    }
#pragma unroll
    for (int s = 0; s < 8; s++) {
      bf16x8 bu[6], bw[6];
#pragma unroll
      for (int ti = 0; ti < 6; ti++) {
        bu[ti] = *(const bf16x8*)(pU[ti] + s * 32);
        bw[ti] = *(const bf16x8*)(pW[ti] + s * 32);
      }
      size_t xoff = (size_t)(s >> 1) * 16384 + (size_t)t * 64 + (s & 1) * 32 + quad * 8;
#pragma unroll
      for (int mt = 0; mt < 2; mt++) {
        bf16x8 ah = *(const bf16x8*)&hb[(mt * 16 + l16) * 264 + s * 32 + quad * 8];
        bf16x8 ax = *(const bf16x8*)(xbase[mt] + xoff);
#pragma unroll
        for (int ti = 0; ti < 4; ti++) {
          azr[mt][ti] = __builtin_amdgcn_mfma_f32_16x16x32_bf16(ah, bu[ti], azr[mt][ti], 0, 0, 0);
          azr[mt][ti] = __builtin_amdgcn_mfma_f32_16x16x32_bf16(ax, bw[ti], azr[mt][ti], 0, 0, 0);
        }
#pragma unroll
        for (int jj = 0; jj < 2; jj++) {
          arh[mt][jj] = __builtin_amdgcn_mfma_f32_16x16x32_bf16(ah, bu[4 + jj], arh[mt][jj], 0, 0, 0);
          agh[mt][jj] = __builtin_amdgcn_mfma_f32_16x16x32_bf16(ax, bw[4 + jj], agh[mt][jj], 0, 0, 0);
        }
      }
    }
    __syncthreads();
#pragma unroll
    for (int mt = 0; mt < 2; mt++)
#pragma unroll
      for (int jj = 0; jj < 2; jj++)
#pragma unroll
        for (int r = 0; r < 4; r++) {
          int seg = mt * 16 + quad * 4 + r;
          int col = wc * 32 + jj * 16 + l16;
          float z  = sigm(azr[mt][jj][r] + bsZ[jj]);
          float rg = sigm(azr[mt][2 + jj][r] + bsR[jj]);
          float hh = fmaxf(agh[mt][jj][r] + biH[jj] + rg * (arh[mt][jj][r] + brH[jj]), 0.f);
          float hn = z * hreg[mt][jj][r] + (1.0f - z) * hh;
          hreg[mt][jj][r] = hn;
          hb[seg * 264 + col] = f2bf(hn);
        }
    __syncthreads();
  }
#pragma unroll
  for (int mt = 0; mt < 2; mt++)
#pragma unroll
    for (int jj = 0; jj < 2; jj++)
#pragma unroll
      for (int r = 0; r < 4; r++) {
        int seg = mt * 16 + quad * 4 + r;
        int col = wc * 32 + jj * 16 + l16;
        out[(size_t)(n0 + seg) * 256 + col] = hreg[mt][jj][r];
      }
}

// ---------------- host ----------------
extern "C" void kernel_launch(void* const* d_in, const int* in_sizes, int n_in,
                              void* d_out, int out_size, void* d_ws, size_t ws_size,
                              hipStream_t stream) {
  (void)in_sizes; (void)n_in; (void)out_size;
  const float* x      = (const float*)d_in[0];
  const float* conv_w = (const float*)d_in[1];
  const float* conv_b = (const float*)d_in[2];
  const float* attn_w = (const float*)d_in[3];
  const float* attn_b = (const float*)d_in[4];
  const float* gru_w  = (const float*)d_in[5];
  const float* gru_u  = (const float*)d_in[6];
  const float* gru_b  = (const float*)d_in[7];

  char* ws = (char*)d_ws;
  const size_t NEED_A = 537919488;   // xac 128M + gates 384M (x_bf aliased) + weights

  if (ws_size >= NEED_A) {
    // ---- Path A: precomputed gates + fast scan ----
    u16* xac     = (u16*)(ws);                  // 134217728 B
    u16* gates   = (u16*)(ws + 134217728);      // 402653184 B
    u16* x_bf    = (u16*)(ws + 134217728);      // 67108864 B, aliased into gates (dead before K3)
    u16* conv_wT = (u16*)(ws + 536870912);
    u16* attn_wT = (u16*)(ws + 536936448);
    u16* gru_wT  = (u16*)(ws + 537067520);
    u16* gru_uT  = (u16*)(ws + 537460736);

    hipLaunchKernelGGL(k_cvt4, dim3(4096), dim3(256), 0, stream,
                       (const float4*)x, (ushort4*)x_bf, 8388608);
    hipLaunchKernelGGL(k_transp, dim3(128), dim3(256), 0, stream, conv_w, conv_wT, 128, 256);
    hipLaunchKernelGGL(k_transp, dim3(256), dim3(256), 0, stream, attn_w, attn_wT, 256, 256);
    hipLaunchKernelGGL(k_transp, dim3(768), dim3(256), 0, stream, gru_w, gru_wT, 256, 768);
    hipLaunchKernelGGL(k_transp, dim3(768), dim3(256), 0, stream, gru_u, gru_uT, 256, 768);

    hipLaunchKernelGGL((k_gemm<true, true, false>), dim3(2048, 2), dim3(256), 0, stream,
                       x_bf, conv_wT, conv_b, xac, 128, 0);
    hipLaunchKernelGGL(k_attn, dim3(1024, 4), dim3(256), 0, stream,
                       xac, attn_wT, attn_b);
    // K3: gates = x_att @ gru_w + bi  (chunked-A read, row-major out)
    hipLaunchKernelGGL((k_gemm<false, false, true>), dim3(2048, 6), dim3(256), 0, stream,
                       xac, gru_wT, gru_b, gates, 256, 768);
    hipLaunchKernelGGL(k_gruf2, dim3(64), dim3(1024), 0, stream,
                       gates, gru_uT, gru_b + 768, (float*)d_out);
  } else {
    // ---- Path B: round-4 layout + fused scan (known-correct fallback) ----
    const size_t NEED_B = 202309696;
    if (ws_size < NEED_B) return;
    u16* xac     = (u16*)(ws);
    u16* x_bf    = (u16*)(ws + 134217728);
    u16* conv_wT = (u16*)(ws + 201326592);
    u16* attn_wT = (u16*)(ws + 201392128);
    u16* gru_wT  = (u16*)(ws + 201523200);
    u16* gru_uT  = (u16*)(ws + 201916416);

    hipLaunchKernelGGL(k_cvt4, dim3(4096), dim3(256), 0, stream,
                       (const float4*)x, (ushort4*)x_bf, 8388608);
    hipLaunchKernelGGL(k_transp, dim3(128), dim3(256), 0, stream, conv_w, conv_wT, 128, 256);
    hipLaunchKernelGGL(k_transp, dim3(256), dim3(256), 0, stream, attn_w, attn_wT, 256, 256);
    hipLaunchKernelGGL(k_transp, dim3(768), dim3(256), 0, stream, gru_w, gru_wT, 256, 768);
    hipLaunchKernelGGL(k_transp, dim3(768), dim3(256), 0, stream, gru_u, gru_uT, 256, 768);

    hipLaunchKernelGGL((k_gemm<true, true, false>), dim3(2048, 2), dim3(256), 0, stream,
                       x_bf, conv_wT, conv_b, xac, 128, 0);
    hipLaunchKernelGGL(k_attn, dim3(1024, 4), dim3(256), 0, stream,
                       xac, attn_wT, attn_b);
    hipLaunchKernelGGL(k_gruf, dim3(32), dim3(512), 0, stream,
                       xac, gru_uT, gru_wT, gru_b, (float*)d_out);
  }
}

// Round 6
// 1258.548 us; speedup vs baseline: 4.4057x; 4.3734x over previous
//
#include <hip/hip_runtime.h>
#include <stdint.h>

typedef unsigned short u16;
typedef __attribute__((ext_vector_type(8))) __bf16 bf16x8;
typedef __attribute__((ext_vector_type(4))) float f32x4;

#define TTS 256
#define NSEG 1024
#define TC 32            // time-chunk for gates

__device__ __forceinline__ u16 f2bf(float f) {
  union { float f; uint32_t u; } v; v.f = f;
  uint32_t r = v.u + 0x7fffu + ((v.u >> 16) & 1u);
  return (u16)(r >> 16);
}
__device__ __forceinline__ float bf2f(u16 h) {
  union { uint32_t u; float f; } v; v.u = ((uint32_t)h) << 16;
  return v.f;
}
__device__ __forceinline__ float sigm(float x) {
  return __builtin_amdgcn_rcpf(1.0f + __expf(-x));
}

// ---------------- K0: transpose small weight, fp32 -> bf16 ----------------
__global__ void k_transp(const float* __restrict__ in, u16* __restrict__ out, int R, int C) {
  int i = blockIdx.x * blockDim.x + threadIdx.x;
  if (i < R * C) {
    int r = i / C, c = i % C;
    out[(size_t)c * R + r] = f2bf(in[i]);
  }
}

// ---------------- K1/K3c: bf16 MFMA GEMM, 128x128 tile, BK=32 ----------------
// AMODE 0: A fp32 row-major [M][K] (K1: x), convert in-register.
// AMODE 1: A bf16 chunked x_att [seg][k>>6][t][64], rows m = seg*TC + tt, t = t0+tt.
// STORE_T: write chunked convT layout [seg][f>>6][f&63][t]. Else row-major [M][Nld].
template <bool RELU, bool STORE_T, int AMODE>
__global__ __launch_bounds__(256) void k_gemm(
    const void* __restrict__ Av, const u16* __restrict__ Bt,
    const float* __restrict__ bias, u16* __restrict__ out, int K, int Nld, int t0) {
  __shared__ u16 ldsA[4096];
  __shared__ u16 ldsB[4096];
  const int tid  = threadIdx.x;
  const int w    = tid >> 6;
  const int lane = tid & 63;
  const int quad = lane >> 4;
  const int l16  = lane & 15;
  const int m0 = blockIdx.x * 128;
  const int n0 = blockIdx.y * 128;
  const int wm = w >> 1, wn = w & 1;
  const int srow = tid & 127, shalf = tid >> 7;   // staging map

  f32x4 acc[4][4];
#pragma unroll
  for (int i = 0; i < 4; i++)
#pragma unroll
    for (int j = 0; j < 4; j++) acc[i][j] = f32x4{0.f, 0.f, 0.f, 0.f};

  for (int k0 = 0; k0 < K; k0 += 32) {
    ushort4 va[2][2]; bf16x8 vb[2];
#pragma unroll
    for (int q = 0; q < 2; q++) {
      int c = shalf * 2 + q;
      int kk = k0 + c * 8;
      if (AMODE == 0) {
        const float* Af = (const float*)Av;
        float4 f0 = *(const float4*)(Af + (size_t)(m0 + srow) * K + kk);
        float4 f1 = *(const float4*)(Af + (size_t)(m0 + srow) * K + kk + 4);
        va[q][0] = ushort4{f2bf(f0.x), f2bf(f0.y), f2bf(f0.z), f2bf(f0.w)};
        va[q][1] = ushort4{f2bf(f1.x), f2bf(f1.y), f2bf(f1.z), f2bf(f1.w)};
      } else {
        const u16* Ax = (const u16*)Av;
        int r = m0 + srow;
        const bf16x8 v = *(const bf16x8*)(Ax + (size_t)(r >> 5) * 65536 +
                          (size_t)(kk >> 6) * 16384 + (t0 + (r & 31)) * 64 + (kk & 63));
        va[q][0] = ((const ushort4*)&v)[0];
        va[q][1] = ((const ushort4*)&v)[1];
      }
      vb[q] = *(const bf16x8*)(Bt + (size_t)(n0 + srow) * K + kk);
    }
    __syncthreads();  // prior iteration's ds_reads complete before overwrite
#pragma unroll
    for (int q = 0; q < 2; q++) {
      int c = shalf * 2 + q;
      *(ushort4*)&ldsA[(c * 128 + srow) * 8]     = va[q][0];
      *(ushort4*)&ldsA[(c * 128 + srow) * 8 + 4] = va[q][1];
      *(bf16x8*)&ldsB[(c * 128 + srow) * 8] = vb[q];
    }
    __syncthreads();
    bf16x8 a[4], b[4];
#pragma unroll
    for (int i = 0; i < 4; i++)
      a[i] = *(const bf16x8*)&ldsA[(quad * 128 + wm * 64 + i * 16 + l16) * 8];
#pragma unroll
    for (int j = 0; j < 4; j++)
      b[j] = *(const bf16x8*)&ldsB[(quad * 128 + wn * 64 + j * 16 + l16) * 8];
#pragma unroll
    for (int i = 0; i < 4; i++)
#pragma unroll
      for (int j = 0; j < 4; j++)
        acc[i][j] = __builtin_amdgcn_mfma_f32_16x16x32_bf16(a[i], b[j], acc[i][j], 0, 0, 0);
  }

#pragma unroll
  for (int j = 0; j < 4; j++) {
    int col = n0 + wn * 64 + j * 16 + l16;
    float bv = bias[col];
#pragma unroll
    for (int i = 0; i < 4; i++) {
      int row0 = m0 + wm * 64 + i * 16 + quad * 4;  // 4 consecutive rows
      if (STORE_T) {
        int nseg = row0 >> 8, tt0 = row0 & 255;
        ushort4 o;
        float v0 = acc[i][j][0] + bv, v1 = acc[i][j][1] + bv;
        float v2 = acc[i][j][2] + bv, v3 = acc[i][j][3] + bv;
        if (RELU) {
          v0 = fmaxf(v0, 0.f); v1 = fmaxf(v1, 0.f);
          v2 = fmaxf(v2, 0.f); v3 = fmaxf(v3, 0.f);
        }
        o.x = f2bf(v0); o.y = f2bf(v1); o.z = f2bf(v2); o.w = f2bf(v3);
        *(ushort4*)&out[(size_t)nseg * 65536 + (size_t)(col >> 6) * 16384 +
                        (col & 63) * 256 + tt0] = o;
      } else {
#pragma unroll
        for (int r = 0; r < 4; r++) {
          float v = acc[i][j][r] + bv;
          if (RELU) v = fmaxf(v, 0.f);
          out[(size_t)(row0 + r) * Nld + col] = f2bf(v);
        }
      }
    }
  }
}

// ---------------- K2: attention (in-place on xac), plain-load staging ----------------
__global__ __launch_bounds__(256) void k_attn(
    u16* xac,
    const u16* __restrict__ Wt,       // attn_w^T: [t'][t] 256x256
    const float* __restrict__ attn_b) {
  __shared__ u16 ldsW[8192];          // per-stage Wt tile [c 4][t' 256][8]
  __shared__ u16 ldsC[16384];         // conv resident [tchunk 32][f 64][8]
  __shared__ float redmax[4][64];
  __shared__ float redsum[4][64];
  const int tid  = threadIdx.x;
  const int w    = tid >> 6;
  const int lane = tid & 63;
  const int quad = lane >> 4;
  const int l16  = lane & 15;
  const int seg = blockIdx.x;
  const int c4  = blockIdx.y;
  u16* reg = xac + (size_t)seg * 65536 + (size_t)c4 * 16384;

  {
    const int f = tid & 63, g = tid >> 6;
#pragma unroll
    for (int u = 0; u < 8; u++) {
      int tch = g * 8 + u;
      *(bf16x8*)&ldsC[(tch * 64 + f) * 8] =
          *(const bf16x8*)(reg + (size_t)f * 256 + tch * 8);
    }
  }

  f32x4 acc[4][4];
#pragma unroll
  for (int i = 0; i < 4; i++)
#pragma unroll
    for (int j = 0; j < 4; j++) acc[i][j] = f32x4{0.f, 0.f, 0.f, 0.f};

  for (int s = 0; s < 8; s++) {
    int k0 = s * 32;
    bf16x8 vw[4];
#pragma unroll
    for (int c = 0; c < 4; c++)
      vw[c] = *(const bf16x8*)(Wt + (size_t)tid * 256 + k0 + c * 8);
    __syncthreads();
#pragma unroll
    for (int c = 0; c < 4; c++)
      *(bf16x8*)&ldsW[(c * 256 + tid) * 8] = vw[c];
    __syncthreads();
    bf16x8 a[4], b[4];
#pragma unroll
    for (int i = 0; i < 4; i++)
      a[i] = *(const bf16x8*)&ldsW[(quad * 256 + w * 64 + i * 16 + l16) * 8];
#pragma unroll
    for (int j = 0; j < 4; j++)
      b[j] = *(const bf16x8*)&ldsC[((s * 4 + quad) * 64 + j * 16 + l16) * 8];
#pragma unroll
    for (int i = 0; i < 4; i++)
#pragma unroll
      for (int j = 0; j < 4; j++)
        acc[i][j] = __builtin_amdgcn_mfma_f32_16x16x32_bf16(a[i], b[j], acc[i][j], 0, 0, 0);
  }

#pragma unroll
  for (int i = 0; i < 4; i++)
#pragma unroll
    for (int r = 0; r < 4; r++) {
      float ab = attn_b[w * 64 + i * 16 + quad * 4 + r];
#pragma unroll
      for (int j = 0; j < 4; j++) acc[i][j][r] += ab;
    }

  float lmax[4];
#pragma unroll
  for (int j = 0; j < 4; j++) {
    float m = -1e30f;
#pragma unroll
    for (int i = 0; i < 4; i++)
#pragma unroll
      for (int r = 0; r < 4; r++) m = fmaxf(m, acc[i][j][r]);
    m = fmaxf(m, __shfl_xor(m, 16));
    m = fmaxf(m, __shfl_xor(m, 32));
    lmax[j] = m;
  }
  __syncthreads();
  if (quad == 0) {
#pragma unroll
    for (int j = 0; j < 4; j++) redmax[w][j * 16 + l16] = lmax[j];
  }
  __syncthreads();
  float gmax[4];
#pragma unroll
  for (int j = 0; j < 4; j++) {
    int c = j * 16 + l16;
    gmax[j] = fmaxf(fmaxf(redmax[0][c], redmax[1][c]), fmaxf(redmax[2][c], redmax[3][c]));
  }
  float lsum[4];
#pragma unroll
  for (int j = 0; j < 4; j++) {
    float sacc = 0.f;
#pragma unroll
    for (int i = 0; i < 4; i++)
#pragma unroll
      for (int r = 0; r < 4; r++) {
        float e = __expf(acc[i][j][r] - gmax[j]);
        acc[i][j][r] = e;
        sacc += e;
      }
    sacc += __shfl_xor(sacc, 16);
    sacc += __shfl_xor(sacc, 32);
    lsum[j] = sacc;
  }
  if (quad == 0) {
#pragma unroll
    for (int j = 0; j < 4; j++) redsum[w][j * 16 + l16] = lsum[j];
  }
  __syncthreads();
  float rinv[4];
#pragma unroll
  for (int j = 0; j < 4; j++) {
    int c = j * 16 + l16;
    rinv[j] = 1.0f / (redsum[0][c] + redsum[1][c] + redsum[2][c] + redsum[3][c]);
  }

#pragma unroll
  for (int i = 0; i < 4; i++) {
#pragma unroll
    for (int r = 0; r < 4; r++) {
      int tp = w * 64 + i * 16 + quad * 4 + r;
#pragma unroll
      for (int j = 0; j < 4; j++) {
        int fl = j * 16 + l16;
        float cv = bf2f(ldsC[((tp >> 3) * 64 + fl) * 8 + (tp & 7)]);
        float xa = acc[i][j][r] * rinv[j] * cv;
        reg[(size_t)tp * 64 + fl] = f2bf(xa);
      }
    }
  }
}

// ---------------- K4c: GRU scan over one time chunk (TC steps) ----------------
// 64 blocks x 512 thr (8 waves), 16 segs/block. Ut fragments: 4 of 6 sets
// register-resident (g0 z,r,h + g1 h = 128 VGPR), 2 sets (g1 z,r) staged in
// LDS once per launch. Per-step global traffic: gates only (h-independent).
// h carried between chunks via hio (= d_out) in fp32.
__global__ __launch_bounds__(512, 2) void k_scanc(
    const u16* __restrict__ gc,   // gates chunk [NSEG*TC][768] (x@W + bi)
    const u16* __restrict__ Ut,   // gru_u^T [768][256]
    const float* __restrict__ br, // gru_b[1]: [768]
    float* __restrict__ hio,      // [NSEG][256] fp32 (d_out)
    int init) {
  __shared__ u16 uls[65536];      // [w 8][set 2][s 8][lane 64][8]  = 128 KB
  __shared__ u16 hb[16 * 264];    // bf16 h, row stride 264
  const int tid  = threadIdx.x;
  const int w    = tid >> 6;
  const int lane = tid & 63;
  const int quad = lane >> 4;
  const int l16  = lane & 15;
  const int n0 = blockIdx.x * 16;
  const int cg[2] = {w, 8 + w};   // two col-groups per wave

  // stage g1 z,r Ut fragments into LDS (once)
#pragma unroll
  for (int j = 0; j < 2; j++)
#pragma unroll
    for (int s = 0; s < 8; s++)
      *(bf16x8*)&uls[w * 8192 + (j * 8 + s) * 512 + lane * 8] =
          *(const bf16x8*)(Ut + (size_t)(j * 256 + cg[1] * 16 + l16) * 256 + s * 32 + quad * 8);

  // register-resident Ut fragments: g0 all gates, g1 gate h
  bf16x8 ur0[3][8], urh1[8];
#pragma unroll
  for (int g = 0; g < 3; g++)
#pragma unroll
    for (int s = 0; s < 8; s++)
      ur0[g][s] = *(const bf16x8*)(Ut + (size_t)(g * 256 + cg[0] * 16 + l16) * 256 + s * 32 + quad * 8);
#pragma unroll
  for (int s = 0; s < 8; s++)
    urh1[s] = *(const bf16x8*)(Ut + (size_t)(512 + cg[1] * 16 + l16) * 256 + s * 32 + quad * 8);

  // biases per (group, gate)
  float brZ[2], brR[2], brH[2];
#pragma unroll
  for (int grp = 0; grp < 2; grp++) {
    int c = cg[grp] * 16 + l16;
    brZ[grp] = br[c]; brR[grp] = br[256 + c]; brH[grp] = br[512 + c];
  }

  // h init: registers (this lane's 4 segs x 2 groups) + hb for all 16 segs
  float hreg[2][4];
#pragma unroll
  for (int grp = 0; grp < 2; grp++)
#pragma unroll
    for (int r = 0; r < 4; r++)
      hreg[grp][r] = init ? 0.f
                          : hio[(size_t)(n0 + quad * 4 + r) * 256 + cg[grp] * 16 + l16];
  {
    int sg = tid >> 5, c0 = (tid & 31) * 8;   // 16 segs x 256 cols / 512 thr
    if (init) {
      *(ushort4*)&hb[sg * 264 + c0]     = ushort4{0, 0, 0, 0};
      *(ushort4*)&hb[sg * 264 + c0 + 4] = ushort4{0, 0, 0, 0};
    } else {
      const float* hp = hio + (size_t)(n0 + sg) * 256 + c0;
      float4 h0 = *(const float4*)(hp), h1 = *(const float4*)(hp + 4);
      *(ushort4*)&hb[sg * 264 + c0]     = ushort4{f2bf(h0.x), f2bf(h0.y), f2bf(h0.z), f2bf(h0.w)};
      *(ushort4*)&hb[sg * 264 + c0 + 4] = ushort4{f2bf(h1.x), f2bf(h1.y), f2bf(h1.z), f2bf(h1.w)};
    }
  }
  // gates row bases for this lane's 4 segs
  const u16* gseg[4];
#pragma unroll
  for (int r = 0; r < 4; r++)
    gseg[r] = gc + (size_t)(n0 + quad * 4 + r) * TC * 768;
  __syncthreads();

  for (int tt = 0; tt < TC; tt++) {
    // prefetch gates[tt] (h-independent)
    float gg[2][3][4];
#pragma unroll
    for (int grp = 0; grp < 2; grp++)
#pragma unroll
      for (int g = 0; g < 3; g++)
#pragma unroll
        for (int r = 0; r < 4; r++)
          gg[grp][g][r] = bf2f(gseg[r][tt * 768 + g * 256 + cg[grp] * 16 + l16]);

    f32x4 acc[2][3];
#pragma unroll
    for (int grp = 0; grp < 2; grp++)
#pragma unroll
      for (int g = 0; g < 3; g++) acc[grp][g] = f32x4{0.f, 0.f, 0.f, 0.f};

#pragma unroll
    for (int s = 0; s < 8; s++) {
      bf16x8 ah = *(const bf16x8*)&hb[l16 * 264 + s * 32 + quad * 8];
#pragma unroll
      for (int g = 0; g < 3; g++)
        acc[0][g] = __builtin_amdgcn_mfma_f32_16x16x32_bf16(ah, ur0[g][s], acc[0][g], 0, 0, 0);
      bf16x8 uz = *(const bf16x8*)&uls[w * 8192 + s * 512 + lane * 8];
      bf16x8 urr = *(const bf16x8*)&uls[w * 8192 + (8 + s) * 512 + lane * 8];
      acc[1][0] = __builtin_amdgcn_mfma_f32_16x16x32_bf16(ah, uz,      acc[1][0], 0, 0, 0);
      acc[1][1] = __builtin_amdgcn_mfma_f32_16x16x32_bf16(ah, urr,     acc[1][1], 0, 0, 0);
      acc[1][2] = __builtin_amdgcn_mfma_f32_16x16x32_bf16(ah, urh1[s], acc[1][2], 0, 0, 0);
    }
    __syncthreads();   // all hb reads complete before overwrite

#pragma unroll
    for (int grp = 0; grp < 2; grp++)
#pragma unroll
      for (int r = 0; r < 4; r++) {
        float z  = sigm(acc[grp][0][r] + gg[grp][0][r] + brZ[grp]);
        float rg = sigm(acc[grp][1][r] + gg[grp][1][r] + brR[grp]);
        float hh = fmaxf(gg[grp][2][r] + rg * (acc[grp][2][r] + brH[grp]), 0.f);
        float hn = z * hreg[grp][r] + (1.0f - z) * hh;
        hreg[grp][r] = hn;
        hb[(quad * 4 + r) * 264 + cg[grp] * 16 + l16] = f2bf(hn);
      }
    __syncthreads();   // writes visible before next step's reads
  }

#pragma unroll
  for (int grp = 0; grp < 2; grp++)
#pragma unroll
    for (int r = 0; r < 4; r++)
      hio[(size_t)(n0 + quad * 4 + r) * 256 + cg[grp] * 16 + l16] = hreg[grp][r];
}

// ---------------- host ----------------
extern "C" void kernel_launch(void* const* d_in, const int* in_sizes, int n_in,
                              void* d_out, int out_size, void* d_ws, size_t ws_size,
                              hipStream_t stream) {
  (void)in_sizes; (void)n_in; (void)out_size;
  const float* x      = (const float*)d_in[0];
  const float* conv_w = (const float*)d_in[1];
  const float* conv_b = (const float*)d_in[2];
  const float* attn_w = (const float*)d_in[3];
  const float* attn_b = (const float*)d_in[4];
  const float* gru_w  = (const float*)d_in[5];
  const float* gru_u  = (const float*)d_in[6];
  const float* gru_b  = (const float*)d_in[7];

  // scratch layout: 185,532,416 B total (known-safe: < 202,309,696 proven)
  const size_t NEEDED = 185532416;
  if (ws_size < NEEDED) return;
  char* ws = (char*)d_ws;
  u16* xac     = (u16*)(ws);                  // 134217728 B: convT then x_att (chunked, in-place)
  u16* gatesC  = (u16*)(ws + 134217728);      //  50331648 B: gates for one 32-step chunk
  u16* conv_wT = (u16*)(ws + 184549376);      //     65536 B [f][c]
  u16* attn_wT = (u16*)(ws + 184614912);      //    131072 B [t'][t]
  u16* gru_wT  = (u16*)(ws + 184745984);      //    393216 B [j][f]
  u16* gru_uT  = (u16*)(ws + 185139200);      //    393216 B [j][k]

  hipLaunchKernelGGL(k_transp, dim3(128), dim3(256), 0, stream, conv_w, conv_wT, 128, 256);
  hipLaunchKernelGGL(k_transp, dim3(256), dim3(256), 0, stream, attn_w, attn_wT, 256, 256);
  hipLaunchKernelGGL(k_transp, dim3(768), dim3(256), 0, stream, gru_w, gru_wT, 256, 768);
  hipLaunchKernelGGL(k_transp, dim3(768), dim3(256), 0, stream, gru_u, gru_uT, 256, 768);

  // K1: conv = relu(x @ conv_w + b), fp32 A read + in-register bf16 convert
  hipLaunchKernelGGL((k_gemm<true, true, 0>), dim3(2048, 2), dim3(256), 0, stream,
                     (const void*)x, conv_wT, conv_b, xac, 128, 0, 0);
  // K2: attention softmax + multiply, in place on xac
  hipLaunchKernelGGL(k_attn, dim3(1024, 4), dim3(256), 0, stream,
                     xac, attn_wT, attn_b);
  // K3c/K4c: 8 time chunks of (gates GEMM -> 32-step scan); h lives in d_out
  for (int c = 0; c < 8; c++) {
    hipLaunchKernelGGL((k_gemm<false, false, 1>), dim3(256, 6), dim3(256), 0, stream,
                       (const void*)xac, gru_wT, gru_b, gatesC, 256, 768, c * TC);
    hipLaunchKernelGGL(k_scanc, dim3(64), dim3(512), 0, stream,
                       gatesC, gru_uT, gru_b + 768, (float*)d_out, c == 0 ? 1 : 0);
  }
}